// Round 5
// baseline (544.398 us; speedup 1.0000x reference)
//
#include <hip/hip_runtime.h>
#include <math.h>

#define PIX 36864          // 192*192
#define IMW 192
#define NWIN 4465          // 47*95
#define NWIN_W 95
#define NTASK (NWIN * 6)

typedef short bf16x8 __attribute__((ext_vector_type(8)));
typedef short bf16x4 __attribute__((ext_vector_type(4)));
typedef float floatx4 __attribute__((ext_vector_type(4)));

#if defined(__has_builtin)
#  if __has_builtin(__builtin_amdgcn_rcpf)
#    define RCP(x) __builtin_amdgcn_rcpf(x)
#  endif
#endif
#ifndef RCP
#  define RCP(x) (1.0f / (x))
#endif

__device__ __forceinline__ unsigned short f2bf(float f) {
    union { float f; unsigned u; } v; v.f = f;
    unsigned r = v.u + 0x7fff + ((v.u >> 16) & 1);   // RNE
    return (unsigned short)(r >> 16);
}
__device__ __forceinline__ float bf2f(unsigned short b) {
    union { unsigned u; float f; } v; v.u = ((unsigned)b) << 16;
    return v.f;
}

// ======================= weight convert =======================
__global__ __launch_bounds__(256) void wconv_kernel(
    const float* __restrict__ wr, const float* __restrict__ wi,
    unsigned short* __restrict__ outr, unsigned short* __restrict__ outi,
    unsigned short* __restrict__ outni, int n)
{
    int e = blockIdx.x * 256 + threadIdx.x;
    if (e >= n) return;
    outr[e] = f2bf(wr[e]);
    unsigned short b = f2bf(wi[e]);
    outi[e]  = b;
    outni[e] = b ^ 0x8000;
}

// ======================= pack: fp32 planar -> bf16 k8-packed =======================
__global__ __launch_bounds__(256) void pack_kernel(
    const float* __restrict__ sr, const float* __restrict__ si,
    unsigned short* __restrict__ dr, unsigned short* __restrict__ di, int N)
{
    int n  = blockIdx.x * 256 + threadIdx.x;
    int kb = blockIdx.y;
    bf16x8 vr, vi;
#pragma unroll
    for (int j = 0; j < 8; ++j) {
        ((unsigned short*)&vr)[j] = f2bf(sr[(size_t)(kb * 8 + j) * N + n]);
        ((unsigned short*)&vi)[j] = f2bf(si[(size_t)(kb * 8 + j) * N + n]);
    }
    *(bf16x8*)&dr[((size_t)kb * N + n) * 8] = vr;
    *(bf16x8*)&di[((size_t)kb * N + n) * 8] = vi;
}

// pack + BN1 apply fused (x1 = bn1(s1) in packed bf16)
__global__ __launch_bounds__(256) void pack_bn_kernel(
    const float* __restrict__ sr, const float* __restrict__ si,
    const float* __restrict__ stats,
    const float* __restrict__ gr, const float* __restrict__ br,
    const float* __restrict__ gi, const float* __restrict__ bi,
    unsigned short* __restrict__ dr, unsigned short* __restrict__ di, int N)
{
    int n  = blockIdx.x * 256 + threadIdx.x;
    int kb = blockIdx.y;
    bf16x8 vr, vi;
#pragma unroll
    for (int j = 0; j < 8; ++j) {
        int ch = kb * 8 + j;
        float mr = stats[ch * 2],        isr = stats[ch * 2 + 1];
        float mi = stats[(96 + ch) * 2], isi = stats[(96 + ch) * 2 + 1];
        ((unsigned short*)&vr)[j] = f2bf(gr[ch] * (sr[(size_t)ch * N + n] - mr) * isr + br[ch]);
        ((unsigned short*)&vi)[j] = f2bf(gi[ch] * (si[(size_t)ch * N + n] - mi) * isi + bi[ch]);
    }
    *(bf16x8*)&dr[((size_t)kb * N + n) * 8] = vr;
    *(bf16x8*)&di[((size_t)kb * N + n) * 8] = vi;
}

// ======================= complex GEMM via MFMA =======================
// STORE: 0 fp32 planar | 1 k8-packed bf16 (ACT=1: cgelu on acc first)
//        2 qkvb pixel-major slot | 3 s1=x+acc + BN-stat atomics
//        4 s2=acc+bn1(s1) + BN-stat atomics
template<int K, int STORE, int ACT>
__global__ __launch_bounds__(256, 2) void cgemm_mfma_kernel(
    const unsigned short* __restrict__ Wr, const unsigned short* __restrict__ Wi,
    const unsigned short* __restrict__ Wni,
    const unsigned short* __restrict__ Xr, const unsigned short* __restrict__ Xi,
    float* __restrict__ Yr, float* __restrict__ Yi,
    unsigned short* __restrict__ Pr, unsigned short* __restrict__ Pi,
    const float* __restrict__ Er, const float* __restrict__ Ei,
    const float* __restrict__ st1,
    const float* __restrict__ g1r, const float* __restrict__ b1r,
    const float* __restrict__ g1i, const float* __restrict__ b1i,
    float* __restrict__ ssum,
    int N)
{
    const int lane = threadIdx.x & 63;
    const int wave = threadIdx.x >> 6;
    const int g = lane >> 4;
    const int r = lane & 15;
    const int m0 = blockIdx.x * 32;
    const int n0 = blockIdx.y * 256 + wave * 64;

    floatx4 accR[2][4], accI[2][4];
#pragma unroll
    for (int t = 0; t < 2; ++t)
#pragma unroll
        for (int j = 0; j < 4; ++j) {
            accR[t][j] = (floatx4){0.f, 0.f, 0.f, 0.f};
            accI[t][j] = (floatx4){0.f, 0.f, 0.f, 0.f};
        }

    for (int kc = 0; kc < K; kc += 32) {
        bf16x8 awr[2], awi[2], awni[2];
#pragma unroll
        for (int t = 0; t < 2; ++t) {
            size_t wb = (size_t)(m0 + t * 16 + r) * K + kc + g * 8;
            awr[t]  = *(const bf16x8*)&Wr[wb];
            awi[t]  = *(const bf16x8*)&Wi[wb];
            awni[t] = *(const bf16x8*)&Wni[wb];
        }
        bf16x8 bxr[4], bxi[4];
        const size_t krow = (size_t)((kc >> 3) + g);
#pragma unroll
        for (int j = 0; j < 4; ++j) {
            size_t off = (krow * N + n0 + j * 16 + r) * 8;
            bxr[j] = *(const bf16x8*)&Xr[off];
            bxi[j] = *(const bf16x8*)&Xi[off];
        }
#pragma unroll
        for (int t = 0; t < 2; ++t)
#pragma unroll
            for (int j = 0; j < 4; ++j) {
                accR[t][j] = __builtin_amdgcn_mfma_f32_16x16x32_bf16(awr[t],  bxr[j], accR[t][j], 0, 0, 0);
                accR[t][j] = __builtin_amdgcn_mfma_f32_16x16x32_bf16(awni[t], bxi[j], accR[t][j], 0, 0, 0);
                accI[t][j] = __builtin_amdgcn_mfma_f32_16x16x32_bf16(awr[t],  bxi[j], accI[t][j], 0, 0, 0);
                accI[t][j] = __builtin_amdgcn_mfma_f32_16x16x32_bf16(awi[t],  bxr[j], accI[t][j], 0, 0, 0);
            }
    }

    if (ACT == 1) {   // cgelu on fp32 accumulators
#pragma unroll
        for (int t = 0; t < 2; ++t)
#pragma unroll
            for (int j = 0; j < 4; ++j)
#pragma unroll
                for (int reg = 0; reg < 4; ++reg) {
                    float a = accR[t][j][reg], b = accI[t][j][reg];
                    float mag = sqrtf(a * a + b * b);
                    float f = (0.5f + 0.5f * erff(mag * 0.70710678118654752f)) * mag * RCP(mag + 1e-8f);
                    accR[t][j][reg] = a * f;
                    accI[t][j][reg] = b * f;
                }
    }

    if (STORE == 0) {
#pragma unroll
        for (int t = 0; t < 2; ++t)
#pragma unroll
            for (int j = 0; j < 4; ++j) {
                int col = n0 + j * 16 + r;
#pragma unroll
                for (int reg = 0; reg < 4; ++reg) {
                    int row = m0 + t * 16 + g * 4 + reg;
                    Yr[(size_t)row * N + col] = accR[t][j][reg];
                    Yi[(size_t)row * N + col] = accI[t][j][reg];
                }
            }
    } else if (STORE == 1) {
#pragma unroll
        for (int t = 0; t < 2; ++t)
#pragma unroll
            for (int j = 0; j < 4; ++j) {
                int col = n0 + j * 16 + r;
                size_t rowblk = (size_t)((m0 + t * 16 + g * 4) >> 3);
                int sub = (g & 1) * 4;
                bf16x4 pr, pi;
#pragma unroll
                for (int reg = 0; reg < 4; ++reg) {
                    ((unsigned short*)&pr)[reg] = f2bf(accR[t][j][reg]);
                    ((unsigned short*)&pi)[reg] = f2bf(accI[t][j][reg]);
                }
                *(bf16x4*)&Pr[(rowblk * N + col) * 8 + sub] = pr;
                *(bf16x4*)&Pi[(rowblk * N + col) * 8 + sub] = pi;
            }
    } else if (STORE == 2) {
#pragma unroll
        for (int t = 0; t < 2; ++t) {
            int ch0 = m0 + t * 16;
            int which = ch0 / 96;
            int hh = (ch0 % 96) / 16;
#pragma unroll
            for (int j = 0; j < 4; ++j) {
                int col = n0 + j * 16 + r;
                bf16x4 pr, pi;
#pragma unroll
                for (int reg = 0; reg < 4; ++reg) {
                    ((unsigned short*)&pr)[reg] = f2bf(accR[t][j][reg]);
                    ((unsigned short*)&pi)[reg] = f2bf(accI[t][j][reg]);
                }
                size_t sb = (((size_t)col * 3 + which) * 6 + hh) * 32;
                *(bf16x4*)&Pr[sb + g * 4]      = pr;
                *(bf16x4*)&Pr[sb + 16 + g * 4] = pi;
            }
        }
    } else {   // STORE 3 / 4: fused residual + BN stats
        float sR[2][4], qR[2][4], sI[2][4], qI[2][4];
#pragma unroll
        for (int t = 0; t < 2; ++t)
#pragma unroll
            for (int reg = 0; reg < 4; ++reg) { sR[t][reg]=0.f; qR[t][reg]=0.f; sI[t][reg]=0.f; qI[t][reg]=0.f; }

#pragma unroll
        for (int t = 0; t < 2; ++t)
#pragma unroll
            for (int reg = 0; reg < 4; ++reg) {
                int ch = m0 + t * 16 + g * 4 + reg;
                float m1r=0.f, i1r=0.f, m1i=0.f, i1i=0.f, gr_=0.f, br_=0.f, gi_=0.f, bi_=0.f;
                if (STORE == 4) {
                    m1r = st1[ch * 2];        i1r = st1[ch * 2 + 1];
                    m1i = st1[(96 + ch) * 2]; i1i = st1[(96 + ch) * 2 + 1];
                    gr_ = g1r[ch]; br_ = b1r[ch]; gi_ = g1i[ch]; bi_ = b1i[ch];
                }
#pragma unroll
                for (int j = 0; j < 4; ++j) {
                    int col = n0 + j * 16 + r;
                    float er = Er[(size_t)ch * N + col];
                    float ei = Ei[(size_t)ch * N + col];
                    float vr, vi;
                    if (STORE == 3) {
                        vr = accR[t][j][reg] + er;
                        vi = accI[t][j][reg] + ei;
                    } else {
                        vr = accR[t][j][reg] + gr_ * (er - m1r) * i1r + br_;
                        vi = accI[t][j][reg] + gi_ * (ei - m1i) * i1i + bi_;
                    }
                    Yr[(size_t)ch * N + col] = vr;
                    Yi[(size_t)ch * N + col] = vi;
                    sR[t][reg] += vr; qR[t][reg] += vr * vr;
                    sI[t][reg] += vi; qI[t][reg] += vi * vi;
                }
            }
#pragma unroll
        for (int t = 0; t < 2; ++t)
#pragma unroll
            for (int reg = 0; reg < 4; ++reg) {
                float a0 = sR[t][reg], a1 = qR[t][reg], a2 = sI[t][reg], a3 = qI[t][reg];
#pragma unroll
                for (int msk = 1; msk <= 8; msk <<= 1) {
                    a0 += __shfl_xor(a0, msk, 64);
                    a1 += __shfl_xor(a1, msk, 64);
                    a2 += __shfl_xor(a2, msk, 64);
                    a3 += __shfl_xor(a3, msk, 64);
                }
                if (r == 0) {
                    int ch = m0 + t * 16 + g * 4 + reg;
                    atomicAdd(&ssum[ch * 2],            a0);
                    atomicAdd(&ssum[ch * 2 + 1],        a1);
                    atomicAdd(&ssum[(96 + ch) * 2],     a2);
                    atomicAdd(&ssum[(96 + ch) * 2 + 1], a3);
                }
            }
    }
}

// ======================= finalize BN stats: (sum,sumsq) -> (mean, rsqrt) =======================
__global__ __launch_bounds__(192) void finalize_stats_kernel(
    const float* __restrict__ ssum, float* __restrict__ stats)
{
    int idx = threadIdx.x;
    if (idx >= 192) return;
    float s  = ssum[idx * 2];
    float sq = ssum[idx * 2 + 1];
    float mean = s / (float)PIX;
    float var  = sq / (float)PIX - mean * mean;
    stats[idx * 2]     = mean;
    stats[idx * 2 + 1] = rsqrtf(var + 1e-5f);
}

// ======================= MFMA attention: one wave per (window, head) =======================
__global__ __launch_bounds__(256) void attn_mfma_kernel(
    const unsigned short* __restrict__ qkvb,
    const float* __restrict__ rel,
    unsigned short* __restrict__ wout)
{
    __shared__ unsigned aLDS[4][32 * 36];
    __shared__ unsigned vLDS[4][32 * 17];

    const int wv   = threadIdx.x >> 6;
    const int lane = threadIdx.x & 63;
    const int lr   = lane & 15;
    const int g    = lane >> 4;

    int t = blockIdx.x * 4 + wv;
    if (t >= NTASK) t = NTASK - 1;
    const int w = t / 6, h = t % 6;
    const int nh = w / NWIN_W, nw = w % NWIN_W;
    const int r0 = nh * 4, c0 = nw * 2;

    unsigned* AL = aLDS[wv];
    unsigned* VL = vLDS[wv];

    auto slot = [&](int p, int which) -> size_t {
        int gpix = (r0 + (p >> 2)) * IMW + c0 + (p & 3);
        return ((size_t)gpix * 18 + which * 6 + h) * 32;
    };

    // ---- stage V into LDS as (vr,vi) dword pairs [m][d] ----
    {
        int m = lane & 31;
        int half = lane >> 5;
        size_t sv = slot(m, 2);
        const bf16x8 vr = *(const bf16x8*)&qkvb[sv + half * 8];
        const bf16x8 vi = *(const bf16x8*)&qkvb[sv + 16 + half * 8];
#pragma unroll
        for (int j = 0; j < 8; ++j) {
            unsigned pk = (unsigned)(unsigned short)vr[j] |
                          ((unsigned)(unsigned short)vi[j] << 16);
            VL[m * 17 + half * 8 + j] = pk;
        }
    }

    // ---- Q/K fragments: half-select folded into address, conj via xor ----
    const int hoff = (g >> 1) * 16;       // 0 for lo k-half, 16 for hi
    const int loff = (g & 1) * 8;
    const unsigned sm = (g >= 2) ? 0x80008000u : 0u;
    bf16x8 Are[2], Aim[2], Bre[2], Bim[2];
#pragma unroll
    for (int tt = 0; tt < 2; ++tt) {
        size_t sq = slot(tt * 16 + lr, 0);
        size_t sk = slot(tt * 16 + lr, 1);
        Are[tt] = *(const bf16x8*)&qkvb[sq + hoff + loff];          // [qr | qi]
        Aim[tt] = *(const bf16x8*)&qkvb[sq + (16 - hoff) + loff];   // [qi | qr]
        Bre[tt] = *(const bf16x8*)&qkvb[sk + hoff + loff];          // [kr | ki]
        bf16x8 tmp = Bre[tt];
        unsigned* u = (unsigned*)&tmp;
        u[0] ^= sm; u[1] ^= sm; u[2] ^= sm; u[3] ^= sm;
        Bim[tt] = tmp;                                              // [kr | -ki]
    }

    // ---- S = Q·conj(K)^T : 8 MFMAs ----
    const floatx4 z4 = (floatx4){0.f, 0.f, 0.f, 0.f};
    floatx4 Sre[2][2], Sim[2][2];
#pragma unroll
    for (int tn = 0; tn < 2; ++tn)
#pragma unroll
        for (int tm = 0; tm < 2; ++tm) {
            Sre[tn][tm] = __builtin_amdgcn_mfma_f32_16x16x32_bf16(Are[tn], Bre[tm], z4, 0, 0, 0);
            Sim[tn][tm] = __builtin_amdgcn_mfma_f32_16x16x32_bf16(Aim[tn], Bim[tm], z4, 0, 0, 0);
        }

    // ---- scale + bias, write RAW logits transposed into LDS ----
    const float* relh = rel + h * 105;
#pragma unroll
    for (int tn = 0; tn < 2; ++tn)
#pragma unroll
        for (int tm = 0; tm < 2; ++tm) {
            int m = tm * 16 + lr;
            int ym = m >> 2, xm = m & 3;
            int yn = tn * 4 + g;
            int bidx = (yn - ym + 7) * 7 + (3 - xm);
#pragma unroll
            for (int reg = 0; reg < 4; ++reg) {
                float re = Sre[tn][tm][reg] * 0.25f + relh[bidx + reg];
                float im = Sim[tn][tm][reg] * 0.25f;
                int n = tn * 16 + g * 4 + reg;
                AL[n * 36 + m] = (unsigned)f2bf(re) | ((unsigned)f2bf(im) << 16);
            }
        }
    __syncthreads();

    // ---- row-owner magnitude softmax: 2 lanes per row, 1 shuffle ----
    {
        const int row = lane & 31;
        const int half = lane >> 5;
        unsigned* rp = &AL[row * 36 + half * 16];
        unsigned pk[16];
        *(uint4*)&pk[0]  = *(const uint4*)&rp[0];
        *(uint4*)&pk[4]  = *(const uint4*)&rp[4];
        *(uint4*)&pk[8]  = *(const uint4*)&rp[8];
        *(uint4*)&pk[12] = *(const uint4*)&rp[12];
        float re[16], im[16], mg[16];
#pragma unroll
        for (int j = 0; j < 16; ++j) {
            union { unsigned u; float f; } a, b;
            a.u = pk[j] << 16;
            b.u = pk[j] & 0xffff0000u;
            re[j] = a.f; im[j] = b.f;
            mg[j] = sqrtf(a.f * a.f + b.f * b.f);
        }
        float mx = mg[0];
#pragma unroll
        for (int j = 1; j < 16; ++j) mx = fmaxf(mx, mg[j]);
        mx = fmaxf(mx, __shfl_xor(mx, 32, 64));
        float es[16], ss = 0.f;
#pragma unroll
        for (int j = 0; j < 16; ++j) { es[j] = __expf(mg[j] - mx); ss += es[j]; }
        ss += __shfl_xor(ss, 32, 64);
        float inv = RCP(ss);
#pragma unroll
        for (int j = 0; j < 16; ++j) {
            float f = es[j] * inv * RCP(mg[j] + 1e-8f);
            pk[j] = (unsigned)f2bf(re[j] * f) | ((unsigned)f2bf(im[j] * f) << 16);
        }
        *(uint4*)&rp[0]  = *(uint4*)&pk[0];
        *(uint4*)&rp[4]  = *(uint4*)&pk[4];
        *(uint4*)&rp[8]  = *(uint4*)&pk[8];
        *(uint4*)&rp[12] = *(uint4*)&pk[12];
    }
    __syncthreads();

    // ---- P = attn · V : 8 MFMAs ----
    floatx4 Pre[2] = {z4, z4}, Pim[2] = {z4, z4};
#pragma unroll
    for (int kc = 0; kc < 2; ++kc) {
        bf16x8 Bpr, Bpi;
        unsigned* bpr = (unsigned*)&Bpr;
        unsigned* bpi = (unsigned*)&Bpi;
#pragma unroll
        for (int p = 0; p < 4; ++p) {
            unsigned pv = VL[(kc * 16 + g * 4 + p) * 17 + lr];
            bpr[p] = pv ^ 0x80000000u;            // (vr, -vi)
            bpi[p] = (pv >> 16) | (pv << 16);     // (vi, vr)
        }
#pragma unroll
        for (int tn = 0; tn < 2; ++tn) {
            bf16x8 Af = *(bf16x8*)&AL[(tn * 16 + lr) * 36 + kc * 16 + g * 4];
            Pre[tn] = __builtin_amdgcn_mfma_f32_16x16x32_bf16(Af, Bpr, Pre[tn], 0, 0, 0);
            Pim[tn] = __builtin_amdgcn_mfma_f32_16x16x32_bf16(Af, Bpi, Pim[tn], 0, 0, 0);
        }
    }

    // ---- epilogue: wout[win][pix][ch][re,im] ----
#pragma unroll
    for (int tn = 0; tn < 2; ++tn)
#pragma unroll
        for (int reg = 0; reg < 4; ++reg) {
            int n = tn * 16 + g * 4 + reg;
            int ch = h * 16 + lr;
            unsigned pk = (unsigned)f2bf(Pre[tn][reg]) |
                          ((unsigned)f2bf(Pim[tn][reg]) << 16);
            *(unsigned*)&wout[(((size_t)w * 32 + n) * 96 + ch) * 2] = pk;
        }
}

// ======================= fold + count-div + pack for proj =======================
__global__ __launch_bounds__(256) void fold_pack_kernel(
    const unsigned short* __restrict__ wout,
    unsigned short* __restrict__ dr, unsigned short* __restrict__ di)
{
    int e = blockIdx.x * 256 + threadIdx.x;   // PIX*12
    int gpix = e / 12;
    int kb   = e % 12;
    int r = gpix / IMW, c = gpix % IMW;
    int nh0 = (r >= 7) ? ((r - 4) >> 2) : 0;
    int nh1 = min(46, r >> 2);
    int nw0 = (c >= 3) ? ((c - 2) >> 1) : 0;
    int nw1 = min(94, c >> 1);

    float accr[8] = {0,0,0,0,0,0,0,0}, acci[8] = {0,0,0,0,0,0,0,0};
    int cnt = 0;
    for (int nh = nh0; nh <= nh1; ++nh)
        for (int nw = nw0; nw <= nw1; ++nw) {
            int win = nh * NWIN_W + nw;
            int n = (r - nh * 4) * 4 + (c - nw * 2);
            const unsigned short* src = &wout[(((size_t)win * 32 + n) * 96 + kb * 8) * 2];
            bf16x8 a = *(const bf16x8*)&src[0];
            bf16x8 b = *(const bf16x8*)&src[8];
#pragma unroll
            for (int j = 0; j < 4; ++j) {
                accr[j]     += bf2f((unsigned short)a[j*2]);
                acci[j]     += bf2f((unsigned short)a[j*2+1]);
                accr[4 + j] += bf2f((unsigned short)b[j*2]);
                acci[4 + j] += bf2f((unsigned short)b[j*2+1]);
            }
            ++cnt;
        }
    float invc = 1.0f / ((float)cnt + 1e-8f);
    bf16x8 pr, pi;
#pragma unroll
    for (int j = 0; j < 8; ++j) {
        ((unsigned short*)&pr)[j] = f2bf(accr[j] * invc);
        ((unsigned short*)&pi)[j] = f2bf(acci[j] * invc);
    }
    *(bf16x8*)&dr[((size_t)kb * PIX + gpix) * 8] = pr;
    *(bf16x8*)&di[((size_t)kb * PIX + gpix) * 8] = pi;
}

// ======================= final BN apply =======================
__global__ __launch_bounds__(256) void bn_apply_kernel(
    const float* __restrict__ sr, const float* __restrict__ si,
    const float* __restrict__ gr, const float* __restrict__ br,
    const float* __restrict__ gi, const float* __restrict__ bi,
    const float* __restrict__ stats,
    float* __restrict__ outr, float* __restrict__ outi)
{
    int e = blockIdx.x * 256 + threadIdx.x;
    if (e >= 96 * PIX) return;
    int ch = e / PIX;
    float mr = stats[ch * 2],        isr = stats[ch * 2 + 1];
    float mi = stats[(96 + ch) * 2], isi = stats[(96 + ch) * 2 + 1];
    outr[e] = gr[ch] * (sr[e] - mr) * isr + br[ch];
    outi[e] = gi[ch] * (si[e] - mi) * isi + bi[ch];
}

// ======================= launch =======================
extern "C" void kernel_launch(void* const* d_in, const int* in_sizes, int n_in,
                              void* d_out, int out_size, void* d_ws, size_t ws_size,
                              hipStream_t stream)
{
    const float* x_r     = (const float*)d_in[0];
    const float* x_i     = (const float*)d_in[1];
    const float* qkv_wr  = (const float*)d_in[2];
    const float* qkv_wi  = (const float*)d_in[3];
    const float* proj_wr = (const float*)d_in[4];
    const float* proj_wi = (const float*)d_in[5];
    const float* rel     = (const float*)d_in[6];
    const float* mlp1_wr = (const float*)d_in[7];
    const float* mlp1_wi = (const float*)d_in[8];
    const float* mlp2_wr = (const float*)d_in[9];
    const float* mlp2_wi = (const float*)d_in[10];
    const float* n1_gr   = (const float*)d_in[11];
    const float* n1_br   = (const float*)d_in[12];
    const float* n1_gi   = (const float*)d_in[13];
    const float* n1_bi   = (const float*)d_in[14];
    const float* n2_gr   = (const float*)d_in[15];
    const float* n2_br   = (const float*)d_in[16];
    const float* n2_gi   = (const float*)d_in[17];
    const float* n2_bi   = (const float*)d_in[18];

    const size_t P = PIX;
    char* base = (char*)d_ws;

    unsigned short* Dr = (unsigned short*)base;           // 96*P packed operand
    unsigned short* Di = Dr + 96 * P;
    float* B_r = (float*)(Di + 96 * P);                   // s1 fp32 planar
    float* B_i = B_r + 96 * P;
    char*  R   = (char*)(B_i + 96 * P);                   // overlay region
    unsigned short* qkvb = (unsigned short*)R;            // 576*P ushorts
    unsigned short* wout = qkvb + 576 * P;                // NWIN*32*96*2 ushorts
    float* A_r = (float*)R;                               // s2 (mlp2 out)
    float* A_i = A_r + 96 * P;
    unsigned short* hid_r = (unsigned short*)(A_i + 96 * P);   // 384*P packed hidden
    unsigned short* hid_i = hid_r + 384 * P;
    unsigned short* Wb = wout + (size_t)NWIN * 32 * 96 * 2;    // weights bf16
    float* stats1 = (float*)(Wb + 331776);
    float* stats2 = stats1 + 384;
    float* ssum1  = stats2 + 384;
    float* ssum2  = ssum1 + 384;

    unsigned short* wq_r  = Wb;            unsigned short* wq_i  = Wb + 27648;  unsigned short* wq_ni = Wb + 55296;
    unsigned short* wp_r  = Wb + 82944;    unsigned short* wp_i  = Wb + 92160;  unsigned short* wp_ni = Wb + 101376;
    unsigned short* w1_r  = Wb + 110592;   unsigned short* w1_i  = Wb + 147456; unsigned short* w1_ni = Wb + 184320;
    unsigned short* w2_r  = Wb + 221184;   unsigned short* w2_i  = Wb + 258048; unsigned short* w2_ni = Wb + 294912;

    float* out_r = (float*)d_out;
    float* out_i = out_r + 96 * P;

    dim3 blk(256);

    // 0. zero the BN stat accumulators; weights -> bf16
    hipMemsetAsync(ssum1, 0, 768 * sizeof(float), stream);
    wconv_kernel<<<dim3(108), blk, 0, stream>>>(qkv_wr, qkv_wi, wq_r, wq_i, wq_ni, 27648);
    wconv_kernel<<<dim3(36),  blk, 0, stream>>>(proj_wr, proj_wi, wp_r, wp_i, wp_ni, 9216);
    wconv_kernel<<<dim3(144), blk, 0, stream>>>(mlp1_wr, mlp1_wi, w1_r, w1_i, w1_ni, 36864);
    wconv_kernel<<<dim3(144), blk, 0, stream>>>(mlp2_wr, mlp2_wi, w2_r, w2_i, w2_ni, 36864);

    // 1. pack x
    pack_kernel<<<dim3(144, 12), blk, 0, stream>>>(x_r, x_i, Dr, Di, PIX);
    // 2. QKV gemm -> comp-planar pixel-major qkvb
    cgemm_mfma_kernel<96, 2, 0><<<dim3(9, 144), blk, 0, stream>>>(
        wq_r, wq_i, wq_ni, Dr, Di, nullptr, nullptr, qkvb, nullptr,
        nullptr, nullptr, nullptr, nullptr, nullptr, nullptr, nullptr, nullptr, PIX);
    // 3. MFMA attention -> per-window bf16 outputs
    attn_mfma_kernel<<<dim3((NTASK + 3) / 4), blk, 0, stream>>>(qkvb, rel, wout);
    // 4. fold + /counts + pack for proj
    fold_pack_kernel<<<dim3(1728), blk, 0, stream>>>(wout, Dr, Di);
    // 5. proj gemm -> s1 = x + proj, BN1 stat atomics (fused)
    cgemm_mfma_kernel<96, 3, 0><<<dim3(3, 144), blk, 0, stream>>>(
        wp_r, wp_i, wp_ni, Dr, Di, B_r, B_i, nullptr, nullptr,
        x_r, x_i, nullptr, nullptr, nullptr, nullptr, nullptr, ssum1, PIX);
    // 6. finalize BN1 stats
    finalize_stats_kernel<<<dim3(1), dim3(192), 0, stream>>>(ssum1, stats1);
    // 7. pack + BN1 apply -> packed x1
    pack_bn_kernel<<<dim3(144, 12), blk, 0, stream>>>(B_r, B_i, stats1,
        n1_gr, n1_br, n1_gi, n1_bi, Dr, Di, PIX);
    // 8. mlp1 gemm + fused cgelu -> packed bf16 hidden
    cgemm_mfma_kernel<96, 1, 1><<<dim3(12, 144), blk, 0, stream>>>(
        w1_r, w1_i, w1_ni, Dr, Di, nullptr, nullptr, hid_r, hid_i,
        nullptr, nullptr, nullptr, nullptr, nullptr, nullptr, nullptr, nullptr, PIX);
    // 9. mlp2 gemm -> s2 = m + bn1(s1), BN2 stat atomics (fused)
    cgemm_mfma_kernel<384, 4, 0><<<dim3(3, 144), blk, 0, stream>>>(
        w2_r, w2_i, w2_ni, hid_r, hid_i, A_r, A_i, nullptr, nullptr,
        B_r, B_i, stats1, n1_gr, n1_br, n1_gi, n1_bi, ssum2, PIX);
    // 10. finalize BN2 stats
    finalize_stats_kernel<<<dim3(1), dim3(192), 0, stream>>>(ssum2, stats2);
    // 11. BN2 apply -> out
    bn_apply_kernel<<<dim3(13824), blk, 0, stream>>>(A_r, A_i,
        n2_gr, n2_br, n2_gi, n2_bi, stats2, out_r, out_i);
}

// Round 6
// 382.708 us; speedup vs baseline: 1.4225x; 1.4225x over previous
//
#include <hip/hip_runtime.h>
#include <math.h>

#define PIX 36864          // 192*192
#define IMW 192
#define NWIN 4465          // 47*95
#define NWIN_W 95
#define NTASK (NWIN * 6)

typedef short bf16x8 __attribute__((ext_vector_type(8)));
typedef short bf16x4 __attribute__((ext_vector_type(4)));
typedef float floatx4 __attribute__((ext_vector_type(4)));

#if defined(__has_builtin)
#  if __has_builtin(__builtin_amdgcn_rcpf)
#    define RCP(x) __builtin_amdgcn_rcpf(x)
#  endif
#endif
#ifndef RCP
#  define RCP(x) (1.0f / (x))
#endif

__device__ __forceinline__ unsigned short f2bf(float f) {
    union { float f; unsigned u; } v; v.f = f;
    unsigned r = v.u + 0x7fff + ((v.u >> 16) & 1);   // RNE
    return (unsigned short)(r >> 16);
}
__device__ __forceinline__ float bf2f(unsigned short b) {
    union { unsigned u; float f; } v; v.u = ((unsigned)b) << 16;
    return v.f;
}

// ======================= weight convert =======================
__global__ __launch_bounds__(256) void wconv_kernel(
    const float* __restrict__ wr, const float* __restrict__ wi,
    unsigned short* __restrict__ outr, unsigned short* __restrict__ outi,
    unsigned short* __restrict__ outni, int n)
{
    int e = blockIdx.x * 256 + threadIdx.x;
    if (e >= n) return;
    outr[e] = f2bf(wr[e]);
    unsigned short b = f2bf(wi[e]);
    outi[e]  = b;
    outni[e] = b ^ 0x8000;
}

// ======================= pack: fp32 planar -> bf16 k8-packed =======================
__global__ __launch_bounds__(256) void pack_kernel(
    const float* __restrict__ sr, const float* __restrict__ si,
    unsigned short* __restrict__ dr, unsigned short* __restrict__ di, int N)
{
    int n  = blockIdx.x * 256 + threadIdx.x;
    int kb = blockIdx.y;
    bf16x8 vr, vi;
#pragma unroll
    for (int j = 0; j < 8; ++j) {
        ((unsigned short*)&vr)[j] = f2bf(sr[(size_t)(kb * 8 + j) * N + n]);
        ((unsigned short*)&vi)[j] = f2bf(si[(size_t)(kb * 8 + j) * N + n]);
    }
    *(bf16x8*)&dr[((size_t)kb * N + n) * 8] = vr;
    *(bf16x8*)&di[((size_t)kb * N + n) * 8] = vi;
}

// pack + BN1 apply fused (x1 = bn1(s1) in packed bf16)
__global__ __launch_bounds__(256) void pack_bn_kernel(
    const float* __restrict__ sr, const float* __restrict__ si,
    const float* __restrict__ stats,
    const float* __restrict__ gr, const float* __restrict__ br,
    const float* __restrict__ gi, const float* __restrict__ bi,
    unsigned short* __restrict__ dr, unsigned short* __restrict__ di, int N)
{
    int n  = blockIdx.x * 256 + threadIdx.x;
    int kb = blockIdx.y;
    bf16x8 vr, vi;
#pragma unroll
    for (int j = 0; j < 8; ++j) {
        int ch = kb * 8 + j;
        float mr = stats[ch * 2],        isr = stats[ch * 2 + 1];
        float mi = stats[(96 + ch) * 2], isi = stats[(96 + ch) * 2 + 1];
        ((unsigned short*)&vr)[j] = f2bf(gr[ch] * (sr[(size_t)ch * N + n] - mr) * isr + br[ch]);
        ((unsigned short*)&vi)[j] = f2bf(gi[ch] * (si[(size_t)ch * N + n] - mi) * isi + bi[ch]);
    }
    *(bf16x8*)&dr[((size_t)kb * N + n) * 8] = vr;
    *(bf16x8*)&di[((size_t)kb * N + n) * 8] = vi;
}

// ======================= complex GEMM via MFMA =======================
// STORE: 0 fp32 planar | 1 k8-packed bf16 (ACT=1: cgelu on acc first) | 2 qkvb slot
template<int K, int STORE, int ACT>
__global__ __launch_bounds__(256, 2) void cgemm_mfma_kernel(
    const unsigned short* __restrict__ Wr, const unsigned short* __restrict__ Wi,
    const unsigned short* __restrict__ Wni,
    const unsigned short* __restrict__ Xr, const unsigned short* __restrict__ Xi,
    float* __restrict__ Yr, float* __restrict__ Yi,
    unsigned short* __restrict__ Pr, unsigned short* __restrict__ Pi,
    int N)
{
    const int lane = threadIdx.x & 63;
    const int wave = threadIdx.x >> 6;
    const int g = lane >> 4;
    const int r = lane & 15;
    const int m0 = blockIdx.x * 32;
    const int n0 = blockIdx.y * 256 + wave * 64;

    floatx4 accR[2][4], accI[2][4];
#pragma unroll
    for (int t = 0; t < 2; ++t)
#pragma unroll
        for (int j = 0; j < 4; ++j) {
            accR[t][j] = (floatx4){0.f, 0.f, 0.f, 0.f};
            accI[t][j] = (floatx4){0.f, 0.f, 0.f, 0.f};
        }

    for (int kc = 0; kc < K; kc += 32) {
        bf16x8 awr[2], awi[2], awni[2];
#pragma unroll
        for (int t = 0; t < 2; ++t) {
            size_t wb = (size_t)(m0 + t * 16 + r) * K + kc + g * 8;
            awr[t]  = *(const bf16x8*)&Wr[wb];
            awi[t]  = *(const bf16x8*)&Wi[wb];
            awni[t] = *(const bf16x8*)&Wni[wb];
        }
        bf16x8 bxr[4], bxi[4];
        const size_t krow = (size_t)((kc >> 3) + g);
#pragma unroll
        for (int j = 0; j < 4; ++j) {
            size_t off = (krow * N + n0 + j * 16 + r) * 8;
            bxr[j] = *(const bf16x8*)&Xr[off];
            bxi[j] = *(const bf16x8*)&Xi[off];
        }
#pragma unroll
        for (int t = 0; t < 2; ++t)
#pragma unroll
            for (int j = 0; j < 4; ++j) {
                accR[t][j] = __builtin_amdgcn_mfma_f32_16x16x32_bf16(awr[t],  bxr[j], accR[t][j], 0, 0, 0);
                accR[t][j] = __builtin_amdgcn_mfma_f32_16x16x32_bf16(awni[t], bxi[j], accR[t][j], 0, 0, 0);
                accI[t][j] = __builtin_amdgcn_mfma_f32_16x16x32_bf16(awr[t],  bxi[j], accI[t][j], 0, 0, 0);
                accI[t][j] = __builtin_amdgcn_mfma_f32_16x16x32_bf16(awi[t],  bxr[j], accI[t][j], 0, 0, 0);
            }
    }

    if (ACT == 1) {   // cgelu on fp32 accumulators
#pragma unroll
        for (int t = 0; t < 2; ++t)
#pragma unroll
            for (int j = 0; j < 4; ++j)
#pragma unroll
                for (int reg = 0; reg < 4; ++reg) {
                    float a = accR[t][j][reg], b = accI[t][j][reg];
                    float mag = sqrtf(a * a + b * b);
                    float f = (0.5f + 0.5f * erff(mag * 0.70710678118654752f)) * mag * RCP(mag + 1e-8f);
                    accR[t][j][reg] = a * f;
                    accI[t][j][reg] = b * f;
                }
    }

    if (STORE == 0) {
#pragma unroll
        for (int t = 0; t < 2; ++t)
#pragma unroll
            for (int j = 0; j < 4; ++j) {
                int col = n0 + j * 16 + r;
#pragma unroll
                for (int reg = 0; reg < 4; ++reg) {
                    int row = m0 + t * 16 + g * 4 + reg;
                    Yr[(size_t)row * N + col] = accR[t][j][reg];
                    Yi[(size_t)row * N + col] = accI[t][j][reg];
                }
            }
    } else if (STORE == 1) {
#pragma unroll
        for (int t = 0; t < 2; ++t)
#pragma unroll
            for (int j = 0; j < 4; ++j) {
                int col = n0 + j * 16 + r;
                size_t rowblk = (size_t)((m0 + t * 16 + g * 4) >> 3);
                int sub = (g & 1) * 4;
                bf16x4 pr, pi;
#pragma unroll
                for (int reg = 0; reg < 4; ++reg) {
                    ((unsigned short*)&pr)[reg] = f2bf(accR[t][j][reg]);
                    ((unsigned short*)&pi)[reg] = f2bf(accI[t][j][reg]);
                }
                *(bf16x4*)&Pr[(rowblk * N + col) * 8 + sub] = pr;
                *(bf16x4*)&Pi[(rowblk * N + col) * 8 + sub] = pi;
            }
    } else {
#pragma unroll
        for (int t = 0; t < 2; ++t) {
            int ch0 = m0 + t * 16;
            int which = ch0 / 96;
            int hh = (ch0 % 96) / 16;
#pragma unroll
            for (int j = 0; j < 4; ++j) {
                int col = n0 + j * 16 + r;
                bf16x4 pr, pi;
#pragma unroll
                for (int reg = 0; reg < 4; ++reg) {
                    ((unsigned short*)&pr)[reg] = f2bf(accR[t][j][reg]);
                    ((unsigned short*)&pi)[reg] = f2bf(accI[t][j][reg]);
                }
                size_t sb = (((size_t)col * 3 + which) * 6 + hh) * 32;
                *(bf16x4*)&Pr[sb + g * 4]      = pr;
                *(bf16x4*)&Pr[sb + 16 + g * 4] = pi;
            }
        }
    }
}

// ======================= finalize BN stats =======================
__global__ __launch_bounds__(192) void finalize_stats_kernel(
    const float* __restrict__ ssum, float* __restrict__ stats)
{
    int idx = threadIdx.x;
    if (idx >= 192) return;
    float s  = ssum[idx * 2];
    float sq = ssum[idx * 2 + 1];
    float mean = s / (float)PIX;
    float var  = sq / (float)PIX - mean * mean;
    stats[idx * 2]     = mean;
    stats[idx * 2 + 1] = rsqrtf(var + 1e-5f);
}

// ======================= MFMA attention: one wave per (window, head) =======================
__global__ __launch_bounds__(256) void attn_mfma_kernel(
    const unsigned short* __restrict__ qkvb,
    const float* __restrict__ rel,
    unsigned short* __restrict__ wout)
{
    __shared__ unsigned aLDS[4][32 * 36];
    __shared__ unsigned vLDS[4][32 * 17];

    const int wv   = threadIdx.x >> 6;
    const int lane = threadIdx.x & 63;
    const int lr   = lane & 15;
    const int g    = lane >> 4;

    int t = blockIdx.x * 4 + wv;
    if (t >= NTASK) t = NTASK - 1;
    const int w = t / 6, h = t % 6;
    const int nh = w / NWIN_W, nw = w % NWIN_W;
    const int r0 = nh * 4, c0 = nw * 2;

    unsigned* AL = aLDS[wv];
    unsigned* VL = vLDS[wv];

    auto slot = [&](int p, int which) -> size_t {
        int gpix = (r0 + (p >> 2)) * IMW + c0 + (p & 3);
        return ((size_t)gpix * 18 + which * 6 + h) * 32;
    };

    // ---- stage V into LDS as (vr,vi) dword pairs [m][d] ----
    {
        int m = lane & 31;
        int half = lane >> 5;
        size_t sv = slot(m, 2);
        const bf16x8 vr = *(const bf16x8*)&qkvb[sv + half * 8];
        const bf16x8 vi = *(const bf16x8*)&qkvb[sv + 16 + half * 8];
#pragma unroll
        for (int j = 0; j < 8; ++j) {
            unsigned pk = (unsigned)(unsigned short)vr[j] |
                          ((unsigned)(unsigned short)vi[j] << 16);
            VL[m * 17 + half * 8 + j] = pk;
        }
    }

    // ---- Q/K fragments: half-select folded into address, conj via xor ----
    const int hoff = (g >> 1) * 16;
    const int loff = (g & 1) * 8;
    const unsigned sm = (g >= 2) ? 0x80008000u : 0u;
    bf16x8 Are[2], Aim[2], Bre[2], Bim[2];
#pragma unroll
    for (int tt = 0; tt < 2; ++tt) {
        size_t sq = slot(tt * 16 + lr, 0);
        size_t sk = slot(tt * 16 + lr, 1);
        Are[tt] = *(const bf16x8*)&qkvb[sq + hoff + loff];
        Aim[tt] = *(const bf16x8*)&qkvb[sq + (16 - hoff) + loff];
        Bre[tt] = *(const bf16x8*)&qkvb[sk + hoff + loff];
        bf16x8 tmp = Bre[tt];
        unsigned* u = (unsigned*)&tmp;
        u[0] ^= sm; u[1] ^= sm; u[2] ^= sm; u[3] ^= sm;
        Bim[tt] = tmp;
    }

    // ---- S = Q·conj(K)^T : 8 MFMAs ----
    const floatx4 z4 = (floatx4){0.f, 0.f, 0.f, 0.f};
    floatx4 Sre[2][2], Sim[2][2];
#pragma unroll
    for (int tn = 0; tn < 2; ++tn)
#pragma unroll
        for (int tm = 0; tm < 2; ++tm) {
            Sre[tn][tm] = __builtin_amdgcn_mfma_f32_16x16x32_bf16(Are[tn], Bre[tm], z4, 0, 0, 0);
            Sim[tn][tm] = __builtin_amdgcn_mfma_f32_16x16x32_bf16(Aim[tn], Bim[tm], z4, 0, 0, 0);
        }

    // ---- scale + bias, write RAW logits transposed into LDS ----
    const float* relh = rel + h * 105;
#pragma unroll
    for (int tn = 0; tn < 2; ++tn)
#pragma unroll
        for (int tm = 0; tm < 2; ++tm) {
            int m = tm * 16 + lr;
            int ym = m >> 2, xm = m & 3;
            int yn = tn * 4 + g;
            int bidx = (yn - ym + 7) * 7 + (3 - xm);
#pragma unroll
            for (int reg = 0; reg < 4; ++reg) {
                float re = Sre[tn][tm][reg] * 0.25f + relh[bidx + reg];
                float im = Sim[tn][tm][reg] * 0.25f;
                int n = tn * 16 + g * 4 + reg;
                AL[n * 36 + m] = (unsigned)f2bf(re) | ((unsigned)f2bf(im) << 16);
            }
        }
    __syncthreads();

    // ---- row-owner magnitude softmax: 2 lanes per row, 1 shuffle ----
    {
        const int row = lane & 31;
        const int half = lane >> 5;
        unsigned* rp = &AL[row * 36 + half * 16];
        unsigned pk[16];
        *(uint4*)&pk[0]  = *(const uint4*)&rp[0];
        *(uint4*)&pk[4]  = *(const uint4*)&rp[4];
        *(uint4*)&pk[8]  = *(const uint4*)&rp[8];
        *(uint4*)&pk[12] = *(const uint4*)&rp[12];
        float re[16], im[16], mg[16];
#pragma unroll
        for (int j = 0; j < 16; ++j) {
            union { unsigned u; float f; } a, b;
            a.u = pk[j] << 16;
            b.u = pk[j] & 0xffff0000u;
            re[j] = a.f; im[j] = b.f;
            mg[j] = sqrtf(a.f * a.f + b.f * b.f);
        }
        float mx = mg[0];
#pragma unroll
        for (int j = 1; j < 16; ++j) mx = fmaxf(mx, mg[j]);
        mx = fmaxf(mx, __shfl_xor(mx, 32, 64));
        float es[16], ss = 0.f;
#pragma unroll
        for (int j = 0; j < 16; ++j) { es[j] = __expf(mg[j] - mx); ss += es[j]; }
        ss += __shfl_xor(ss, 32, 64);
        float inv = RCP(ss);
#pragma unroll
        for (int j = 0; j < 16; ++j) {
            float f = es[j] * inv * RCP(mg[j] + 1e-8f);
            pk[j] = (unsigned)f2bf(re[j] * f) | ((unsigned)f2bf(im[j] * f) << 16);
        }
        *(uint4*)&rp[0]  = *(uint4*)&pk[0];
        *(uint4*)&rp[4]  = *(uint4*)&pk[4];
        *(uint4*)&rp[8]  = *(uint4*)&pk[8];
        *(uint4*)&rp[12] = *(uint4*)&pk[12];
    }
    __syncthreads();

    // ---- P = attn · V : 8 MFMAs ----
    floatx4 Pre[2] = {z4, z4}, Pim[2] = {z4, z4};
#pragma unroll
    for (int kc = 0; kc < 2; ++kc) {
        bf16x8 Bpr, Bpi;
        unsigned* bpr = (unsigned*)&Bpr;
        unsigned* bpi = (unsigned*)&Bpi;
#pragma unroll
        for (int p = 0; p < 4; ++p) {
            unsigned pv = VL[(kc * 16 + g * 4 + p) * 17 + lr];
            bpr[p] = pv ^ 0x80000000u;
            bpi[p] = (pv >> 16) | (pv << 16);
        }
#pragma unroll
        for (int tn = 0; tn < 2; ++tn) {
            bf16x8 Af = *(bf16x8*)&AL[(tn * 16 + lr) * 36 + kc * 16 + g * 4];
            Pre[tn] = __builtin_amdgcn_mfma_f32_16x16x32_bf16(Af, Bpr, Pre[tn], 0, 0, 0);
            Pim[tn] = __builtin_amdgcn_mfma_f32_16x16x32_bf16(Af, Bpi, Pim[tn], 0, 0, 0);
        }
    }

    // ---- epilogue ----
#pragma unroll
    for (int tn = 0; tn < 2; ++tn)
#pragma unroll
        for (int reg = 0; reg < 4; ++reg) {
            int n = tn * 16 + g * 4 + reg;
            int ch = h * 16 + lr;
            unsigned pk = (unsigned)f2bf(Pre[tn][reg]) |
                          ((unsigned)f2bf(Pim[tn][reg]) << 16);
            *(unsigned*)&wout[(((size_t)w * 32 + n) * 96 + ch) * 2] = pk;
        }
}

// ======================= fold + count-div + pack for proj =======================
__global__ __launch_bounds__(256) void fold_pack_kernel(
    const unsigned short* __restrict__ wout,
    unsigned short* __restrict__ dr, unsigned short* __restrict__ di)
{
    int e = blockIdx.x * 256 + threadIdx.x;   // PIX*12
    int gpix = e / 12;
    int kb   = e % 12;
    int r = gpix / IMW, c = gpix % IMW;
    int nh0 = (r >= 7) ? ((r - 4) >> 2) : 0;
    int nh1 = min(46, r >> 2);
    int nw0 = (c >= 3) ? ((c - 2) >> 1) : 0;
    int nw1 = min(94, c >> 1);

    float accr[8] = {0,0,0,0,0,0,0,0}, acci[8] = {0,0,0,0,0,0,0,0};
    int cnt = 0;
    for (int nh = nh0; nh <= nh1; ++nh)
        for (int nw = nw0; nw <= nw1; ++nw) {
            int win = nh * NWIN_W + nw;
            int n = (r - nh * 4) * 4 + (c - nw * 2);
            const unsigned short* src = &wout[(((size_t)win * 32 + n) * 96 + kb * 8) * 2];
            bf16x8 a = *(const bf16x8*)&src[0];
            bf16x8 b = *(const bf16x8*)&src[8];
#pragma unroll
            for (int j = 0; j < 4; ++j) {
                accr[j]     += bf2f((unsigned short)a[j*2]);
                acci[j]     += bf2f((unsigned short)a[j*2+1]);
                accr[4 + j] += bf2f((unsigned short)b[j*2]);
                acci[4 + j] += bf2f((unsigned short)b[j*2+1]);
            }
            ++cnt;
        }
    float invc = 1.0f / ((float)cnt + 1e-8f);
    bf16x8 pr, pi;
#pragma unroll
    for (int j = 0; j < 8; ++j) {
        ((unsigned short*)&pr)[j] = f2bf(accr[j] * invc);
        ((unsigned short*)&pi)[j] = f2bf(acci[j] * invc);
    }
    *(bf16x8*)&dr[((size_t)kb * PIX + gpix) * 8] = pr;
    *(bf16x8*)&di[((size_t)kb * PIX + gpix) * 8] = pi;
}

// ======================= fused elementwise + BN-stat kernels =======================
// block-level reduce helper: 4 values -> atomics (ch uniform per block)
__device__ __forceinline__ void block_stats_commit(
    float s_r, float q_r, float s_i, float q_i, int ch, float* __restrict__ ssum)
{
#pragma unroll
    for (int msk = 1; msk < 64; msk <<= 1) {
        s_r += __shfl_xor(s_r, msk, 64);
        q_r += __shfl_xor(q_r, msk, 64);
        s_i += __shfl_xor(s_i, msk, 64);
        q_i += __shfl_xor(q_i, msk, 64);
    }
    __shared__ float red[4][4];
    const int wv = threadIdx.x >> 6;
    if ((threadIdx.x & 63) == 0) {
        red[wv][0] = s_r; red[wv][1] = q_r; red[wv][2] = s_i; red[wv][3] = q_i;
    }
    __syncthreads();
    if (threadIdx.x == 0) {
        float a0 = red[0][0] + red[1][0] + red[2][0] + red[3][0];
        float a1 = red[0][1] + red[1][1] + red[2][1] + red[3][1];
        float a2 = red[0][2] + red[1][2] + red[2][2] + red[3][2];
        float a3 = red[0][3] + red[1][3] + red[2][3] + red[3][3];
        atomicAdd(&ssum[ch * 2],            a0);
        atomicAdd(&ssum[ch * 2 + 1],        a1);
        atomicAdd(&ssum[(96 + ch) * 2],     a2);
        atomicAdd(&ssum[(96 + ch) * 2 + 1], a3);
    }
}

// s1 = x + proj; accumulate BN1 sum/sumsq. grid 96*36, 1024 pix/block (float4)
__global__ __launch_bounds__(256) void combine_stats_kernel(
    const float* __restrict__ xr, const float* __restrict__ xi,
    const float* __restrict__ pr, const float* __restrict__ pi,
    float* __restrict__ sr, float* __restrict__ si,
    float* __restrict__ ssum)
{
    const int ch = blockIdx.x / 36;
    const int pb = blockIdx.x % 36;
    const size_t idx = (size_t)ch * PIX + pb * 1024 + threadIdx.x * 4;
    float4 a = *(const float4*)&xr[idx];
    float4 b = *(const float4*)&pr[idx];
    float4 vr = {a.x + b.x, a.y + b.y, a.z + b.z, a.w + b.w};
    *(float4*)&sr[idx] = vr;
    float4 c = *(const float4*)&xi[idx];
    float4 d = *(const float4*)&pi[idx];
    float4 vi = {c.x + d.x, c.y + d.y, c.z + d.z, c.w + d.w};
    *(float4*)&si[idx] = vi;
    float s_r = vr.x + vr.y + vr.z + vr.w;
    float q_r = vr.x*vr.x + vr.y*vr.y + vr.z*vr.z + vr.w*vr.w;
    float s_i = vi.x + vi.y + vi.z + vi.w;
    float q_i = vi.x*vi.x + vi.y*vi.y + vi.z*vi.z + vi.w*vi.w;
    block_stats_commit(s_r, q_r, s_i, q_i, ch, ssum);
}

// s2 = m + bn1(s1) in place on m; accumulate BN2 sum/sumsq
__global__ __launch_bounds__(256) void addbn_stats_kernel(
    const float* __restrict__ sr, const float* __restrict__ si,
    const float* __restrict__ gr, const float* __restrict__ br,
    const float* __restrict__ gi, const float* __restrict__ bi,
    const float* __restrict__ stats,
    float* __restrict__ mr_, float* __restrict__ mi_,
    float* __restrict__ ssum)
{
    const int ch = blockIdx.x / 36;
    const int pb = blockIdx.x % 36;
    const size_t idx = (size_t)ch * PIX + pb * 1024 + threadIdx.x * 4;
    const float m1r = stats[ch * 2],        i1r = stats[ch * 2 + 1];
    const float m1i = stats[(96 + ch) * 2], i1i = stats[(96 + ch) * 2 + 1];
    const float gr_ = gr[ch], br_ = br[ch], gi_ = gi[ch], bi_ = bi[ch];

    float4 a = *(const float4*)&mr_[idx];
    float4 b = *(const float4*)&sr[idx];
    float4 vr = {a.x + gr_ * (b.x - m1r) * i1r + br_,
                 a.y + gr_ * (b.y - m1r) * i1r + br_,
                 a.z + gr_ * (b.z - m1r) * i1r + br_,
                 a.w + gr_ * (b.w - m1r) * i1r + br_};
    *(float4*)&mr_[idx] = vr;
    float4 c = *(const float4*)&mi_[idx];
    float4 d = *(const float4*)&si[idx];
    float4 vi = {c.x + gi_ * (d.x - m1i) * i1i + bi_,
                 c.y + gi_ * (d.y - m1i) * i1i + bi_,
                 c.z + gi_ * (d.z - m1i) * i1i + bi_,
                 c.w + gi_ * (d.w - m1i) * i1i + bi_};
    *(float4*)&mi_[idx] = vi;
    float s_r = vr.x + vr.y + vr.z + vr.w;
    float q_r = vr.x*vr.x + vr.y*vr.y + vr.z*vr.z + vr.w*vr.w;
    float s_i = vi.x + vi.y + vi.z + vi.w;
    float q_i = vi.x*vi.x + vi.y*vi.y + vi.z*vi.z + vi.w*vi.w;
    block_stats_commit(s_r, q_r, s_i, q_i, ch, ssum);
}

// ======================= final BN apply =======================
__global__ __launch_bounds__(256) void bn_apply_kernel(
    const float* __restrict__ sr, const float* __restrict__ si,
    const float* __restrict__ gr, const float* __restrict__ br,
    const float* __restrict__ gi, const float* __restrict__ bi,
    const float* __restrict__ stats,
    float* __restrict__ outr, float* __restrict__ outi)
{
    int e = blockIdx.x * 256 + threadIdx.x;
    if (e >= 96 * PIX) return;
    int ch = e / PIX;
    float mr = stats[ch * 2],        isr = stats[ch * 2 + 1];
    float mi = stats[(96 + ch) * 2], isi = stats[(96 + ch) * 2 + 1];
    outr[e] = gr[ch] * (sr[e] - mr) * isr + br[ch];
    outi[e] = gi[ch] * (si[e] - mi) * isi + bi[ch];
}

// ======================= launch =======================
extern "C" void kernel_launch(void* const* d_in, const int* in_sizes, int n_in,
                              void* d_out, int out_size, void* d_ws, size_t ws_size,
                              hipStream_t stream)
{
    const float* x_r     = (const float*)d_in[0];
    const float* x_i     = (const float*)d_in[1];
    const float* qkv_wr  = (const float*)d_in[2];
    const float* qkv_wi  = (const float*)d_in[3];
    const float* proj_wr = (const float*)d_in[4];
    const float* proj_wi = (const float*)d_in[5];
    const float* rel     = (const float*)d_in[6];
    const float* mlp1_wr = (const float*)d_in[7];
    const float* mlp1_wi = (const float*)d_in[8];
    const float* mlp2_wr = (const float*)d_in[9];
    const float* mlp2_wi = (const float*)d_in[10];
    const float* n1_gr   = (const float*)d_in[11];
    const float* n1_br   = (const float*)d_in[12];
    const float* n1_gi   = (const float*)d_in[13];
    const float* n1_bi   = (const float*)d_in[14];
    const float* n2_gr   = (const float*)d_in[15];
    const float* n2_br   = (const float*)d_in[16];
    const float* n2_gi   = (const float*)d_in[17];
    const float* n2_bi   = (const float*)d_in[18];

    const size_t P = PIX;
    char* base = (char*)d_ws;

    unsigned short* Dr = (unsigned short*)base;           // 96*P packed operand
    unsigned short* Di = Dr + 96 * P;
    float* B_r = (float*)(Di + 96 * P);                   // s1 fp32 planar
    float* B_i = B_r + 96 * P;
    char*  R   = (char*)(B_i + 96 * P);                   // overlay region
    unsigned short* qkvb = (unsigned short*)R;            // 576*P ushorts
    unsigned short* wout = qkvb + 576 * P;                // NWIN*32*96*2 ushorts
    float* A_r = (float*)R;                               // proj out / m / s2
    float* A_i = A_r + 96 * P;
    unsigned short* hid_r = (unsigned short*)(A_i + 96 * P);   // 384*P packed hidden
    unsigned short* hid_i = hid_r + 384 * P;
    unsigned short* Wb = wout + (size_t)NWIN * 32 * 96 * 2;    // weights bf16
    float* stats1 = (float*)(Wb + 331776);
    float* stats2 = stats1 + 384;
    float* ssum1  = stats2 + 384;
    float* ssum2  = ssum1 + 384;

    unsigned short* wq_r  = Wb;            unsigned short* wq_i  = Wb + 27648;  unsigned short* wq_ni = Wb + 55296;
    unsigned short* wp_r  = Wb + 82944;    unsigned short* wp_i  = Wb + 92160;  unsigned short* wp_ni = Wb + 101376;
    unsigned short* w1_r  = Wb + 110592;   unsigned short* w1_i  = Wb + 147456; unsigned short* w1_ni = Wb + 184320;
    unsigned short* w2_r  = Wb + 221184;   unsigned short* w2_i  = Wb + 258048; unsigned short* w2_ni = Wb + 294912;

    float* out_r = (float*)d_out;
    float* out_i = out_r + 96 * P;

    dim3 blk(256);

    // 0. zero BN stat accumulators (ssum1+ssum2); weights -> bf16
    hipMemsetAsync(ssum1, 0, 768 * sizeof(float), stream);
    wconv_kernel<<<dim3(108), blk, 0, stream>>>(qkv_wr, qkv_wi, wq_r, wq_i, wq_ni, 27648);
    wconv_kernel<<<dim3(36),  blk, 0, stream>>>(proj_wr, proj_wi, wp_r, wp_i, wp_ni, 9216);
    wconv_kernel<<<dim3(144), blk, 0, stream>>>(mlp1_wr, mlp1_wi, w1_r, w1_i, w1_ni, 36864);
    wconv_kernel<<<dim3(144), blk, 0, stream>>>(mlp2_wr, mlp2_wi, w2_r, w2_i, w2_ni, 36864);

    // 1. pack x
    pack_kernel<<<dim3(144, 12), blk, 0, stream>>>(x_r, x_i, Dr, Di, PIX);
    // 2. QKV gemm -> comp-planar pixel-major qkvb
    cgemm_mfma_kernel<96, 2, 0><<<dim3(9, 144), blk, 0, stream>>>(
        wq_r, wq_i, wq_ni, Dr, Di, nullptr, nullptr, qkvb, nullptr, PIX);
    // 3. MFMA attention -> per-window bf16 outputs
    attn_mfma_kernel<<<dim3((NTASK + 3) / 4), blk, 0, stream>>>(qkvb, rel, wout);
    // 4. fold + /counts + pack for proj
    fold_pack_kernel<<<dim3(1728), blk, 0, stream>>>(wout, Dr, Di);
    // 5. proj gemm -> fp32 planar A (plain epilogue — fused version stalled, see R5)
    cgemm_mfma_kernel<96, 0, 0><<<dim3(3, 144), blk, 0, stream>>>(
        wp_r, wp_i, wp_ni, Dr, Di, A_r, A_i, nullptr, nullptr, PIX);
    // 6. s1 = x + proj -> B, BN1 stats accumulated (wide elementwise, latency-hidden)
    combine_stats_kernel<<<dim3(3456), blk, 0, stream>>>(x_r, x_i, A_r, A_i, B_r, B_i, ssum1);
    finalize_stats_kernel<<<dim3(1), dim3(192), 0, stream>>>(ssum1, stats1);
    // 7. pack + BN1 apply -> packed x1
    pack_bn_kernel<<<dim3(144, 12), blk, 0, stream>>>(B_r, B_i, stats1,
        n1_gr, n1_br, n1_gi, n1_bi, Dr, Di, PIX);
    // 8. mlp1 gemm + fused cgelu -> packed bf16 hidden
    cgemm_mfma_kernel<96, 1, 1><<<dim3(12, 144), blk, 0, stream>>>(
        w1_r, w1_i, w1_ni, Dr, Di, nullptr, nullptr, hid_r, hid_i, PIX);
    // 9. mlp2 gemm -> m (fp32 planar A, plain epilogue)
    cgemm_mfma_kernel<384, 0, 0><<<dim3(3, 144), blk, 0, stream>>>(
        w2_r, w2_i, w2_ni, hid_r, hid_i, A_r, A_i, nullptr, nullptr, PIX);
    // 10. s2 = m + bn1(s1) in place on A, BN2 stats accumulated
    addbn_stats_kernel<<<dim3(3456), blk, 0, stream>>>(B_r, B_i,
        n1_gr, n1_br, n1_gi, n1_bi, stats1, A_r, A_i, ssum2);
    finalize_stats_kernel<<<dim3(1), dim3(192), 0, stream>>>(ssum2, stats2);
    // 11. BN2 apply -> out
    bn_apply_kernel<<<dim3(13824), blk, 0, stream>>>(A_r, A_i,
        n2_gr, n2_br, n2_gi, n2_bi, stats2, out_r, out_i);
}